// Round 1
// baseline (1246.567 us; speedup 1.0000x reference)
//
#include <hip/hip_runtime.h>
#include <stdint.h>

#define N_ELEM 262144
#define NC 512       /* coarse scatter buckets */
#define NFINE 131072 /* fine bins = NC * 256; equal-frequency => lambda ~2 */
#define TILE 32768
#define NBLK (N_ELEM / TILE) /* 8 */
#define CAP 1024 /* LDS capacity per coarse bucket; equal-freq => ~512+-15% */

__device__ __forceinline__ unsigned key_of(float x) {
    unsigned u = __float_as_uint(x);
    return u ^ ((u & 0x80000000u) ? 0xFFFFFFFFu : 0x80000000u);
}

// --- Equal-frequency monotone binning ---------------------------------------
// Piecewise-linear approximation of the N(0,1) CDF: 32 segments of width 0.25
// over [-4,4) plus two tail segments. Bins per segment proportional to the
// Gaussian mass of the segment (sum = NFINE exactly). Monotonicity proof:
// within a segment, (x - x0)*slope with slope>0 then floor then clamp is
// monotone non-decreasing in float arithmetic; across a boundary the clamp
// bounds f <= base[s]+cnt[s]-1 < base[s+1]. Correctness of the whole pipeline
// only needs monotone non-decreasing (exact keys order within a fine bin);
// the distribution assumption only affects load balance, and the n>CAP
// fallback in rank_kernel guards arbitrary inputs.
__device__ __constant__ int d_base[35] = {
    0,      4,      11,     30,     75,     176,    389,    812,    1600,
    2979,   5247,   8752,   13843,  20790,  29699,  40435,  52592,  65536,
    78480,  90637,  101373, 110282, 117229, 122320, 125825, 128093, 129472,
    130260, 130683, 130896, 130997, 131042, 131061, 131068, 131072};
__device__ __constant__ float d_slope[34] = {
    1.0f,     28.0f,    76.0f,    180.0f,   404.0f,   852.0f,   1692.0f,
    3152.0f,  5516.0f,  9072.0f,  14020.0f, 20364.0f, 27788.0f, 35636.0f,
    42944.0f, 48628.0f, 51776.0f, 51776.0f, 48628.0f, 42944.0f, 35636.0f,
    27788.0f, 20364.0f, 14020.0f, 9072.0f,  5516.0f,  3152.0f,  1692.0f,
    852.0f,   404.0f,   180.0f,   76.0f,    28.0f,    1.0f};

__device__ __forceinline__ int fine_of_t(float x, const int* __restrict__ b,
                                         const float* __restrict__ sl) {
    int t = (int)floorf((x + 4.0f) * 4.0f); // saturating cvt: monotone
    int seg = t < 0 ? 0 : (t > 31 ? 33 : t + 1);
    float xlo = (seg == 0)
                    ? -8.0f
                    : ((seg == 33) ? 4.0f : (-4.0f + (float)(seg - 1) * 0.25f));
    int cnt = b[seg + 1] - b[seg];
    int v = (int)floorf((x - xlo) * sl[seg]);
    v = v < 0 ? 0 : (v > cnt - 1 ? cnt - 1 : v);
    return b[seg] + v;
}

// --- Kernel A: per-(rowside,block) histogram of 512 coarse buckets ---------
__global__ __launch_bounds__(256) void hist_kernel(
    const float* __restrict__ pred, const float* __restrict__ tru, int r0,
    unsigned* __restrict__ bh) {
    __shared__ unsigned h[NC];
    __shared__ int tb[35];
    __shared__ float ts[34];
    const int rs = blockIdx.y, blk = blockIdx.x;
    const int row = r0 + (rs >> 1);
    const float* x = (rs & 1) ? tru : pred;
    for (int i = threadIdx.x; i < NC; i += 256) h[i] = 0;
    if (threadIdx.x < 35) tb[threadIdx.x] = d_base[threadIdx.x];
    if (threadIdx.x < 34) ts[threadIdx.x] = d_slope[threadIdx.x];
    __syncthreads();
    const float4* p =
        (const float4*)(x + (size_t)row * N_ELEM + (size_t)blk * TILE);
    for (int i = threadIdx.x; i < TILE / 4; i += 256) {
        float4 v = p[i];
        atomicAdd(&h[fine_of_t(v.x, tb, ts) >> 8], 1u);
        atomicAdd(&h[fine_of_t(v.y, tb, ts) >> 8], 1u);
        atomicAdd(&h[fine_of_t(v.z, tb, ts) >> 8], 1u);
        atomicAdd(&h[fine_of_t(v.w, tb, ts) >> 8], 1u);
    }
    __syncthreads();
    unsigned* out = bh + ((size_t)rs * NBLK + blk) * NC;
    for (int i = threadIdx.x; i < NC; i += 256) out[i] = h[i];
}

// --- Kernel B: per-rowside scan -> per-block scatter starts ----------------
// After this, the blk-0 plane holds the rowside-level coarse exclusive prefix.
__global__ __launch_bounds__(512) void scan_kernel(unsigned* __restrict__ bh) {
    __shared__ unsigned ss[NC];
    const int rs = blockIdx.x;
    unsigned* p = bh + (size_t)rs * NBLK * NC;
    const int c = threadIdx.x; // one thread per coarse bucket
    unsigned cnts[NBLK];
    unsigned tot = 0;
    for (int b = 0; b < NBLK; b++) {
        cnts[b] = p[(size_t)b * NC + c];
        tot += cnts[b];
    }
    ss[c] = tot;
    __syncthreads();
    for (int off = 1; off < NC; off <<= 1) {
        unsigned v = (c >= off) ? ss[c - off] : 0u;
        __syncthreads();
        ss[c] += v;
        __syncthreads();
    }
    unsigned pre = ss[c] - tot; // exclusive
    for (int b = 0; b < NBLK; b++) {
        p[(size_t)b * NC + c] = pre;
        pre += cnts[b];
    }
}

// --- Kernel C: scatter (key, sub<<18|idx) grouped by coarse bucket ---------
// 1D grid, XCD-pinned by row (blockIdx%8 heuristic): a row's rec lines are
// dirtied in one XCD's L2 only. Plain stores — L2 accumulates full lines
// (R6 showed nontemporal stores => 3.5x HBM write amplification).
__global__ __launch_bounds__(256) void scatter_kernel(
    const float* __restrict__ pred, const float* __restrict__ tru, int r0,
    int RR, const unsigned* __restrict__ bh, uint2* __restrict__ rec) {
    __shared__ unsigned cur[NC];
    __shared__ int tb[35];
    __shared__ float ts[34];
    const int L = blockIdx.x;
    const int xcd = L & 7;
    const int m = L >> 3;
    const int q = m & 15;
    const int rowGroup = m >> 4;
    const int crow = rowGroup * 8 + xcd;
    if (crow >= RR) return;
    const int side = q & 1, blk = q >> 1;
    const int rs = crow * 2 + side;
    const int row = r0 + crow;
    const float* x = side ? tru : pred;
    const unsigned* st = bh + ((size_t)rs * NBLK + blk) * NC;
    for (int i = threadIdx.x; i < NC; i += 256) cur[i] = st[i];
    if (threadIdx.x < 35) tb[threadIdx.x] = d_base[threadIdx.x];
    if (threadIdx.x < 34) ts[threadIdx.x] = d_slope[threadIdx.x];
    __syncthreads();
    const float4* p =
        (const float4*)(x + (size_t)row * N_ELEM + (size_t)blk * TILE);
    uint2* rr = rec + (size_t)rs * N_ELEM;
    const int ib = blk * TILE;
    for (int i = threadIdx.x; i < TILE / 4; i += 256) {
        float4 v = p[i];
        int i0 = ib + i * 4;
        float vv[4] = {v.x, v.y, v.z, v.w};
#pragma unroll
        for (int k = 0; k < 4; k++) {
            int f = fine_of_t(vv[k], tb, ts);
            unsigned pos = atomicAdd(&cur[f >> 8], 1u);
            rr[pos] = make_uint2(
                key_of(vv[k]),
                ((unsigned)(f & 255) << 18) | (unsigned)(i0 + k));
        }
    }
}

// --- Kernel D: per coarse bucket: LDS counting-sort by 8-bit sub-bin, then
// exact in-sub-bin ordinal rank (~2 compares/element weighted, lambda~2).
// 1D grid, XCD-pinned by row so rp[idx] writes (side 0) / gathers (side 1)
// stay in one L2. side==0: rp0[idx]=rank; side==1: gather, acc S[row].
__global__ __launch_bounds__(256) void rank_kernel(
    const uint2* __restrict__ rec, const unsigned* __restrict__ bh,
    unsigned* __restrict__ rp0, unsigned long long* __restrict__ S, int r0,
    int RR, int side) {
    const int L = blockIdx.x;
    const int xcd = L & 7;
    const int m = L >> 3;
    const int c = m & (NC - 1);
    const int rowGroup = m / NC;
    const int crow = rowGroup * 8 + xcd;
    if (crow >= RR) return;
    const int rs = crow * 2 + side;
    const unsigned* pf = bh + (size_t)rs * NBLK * NC; // blk0 = rowside prefix
    const unsigned base = pf[c];
    const unsigned end = (c + 1 < NC) ? pf[c + 1] : (unsigned)N_ELEM;
    const int n = (int)(end - base);
    const int t = threadIdx.x;
    const uint2* r = rec + (size_t)rs * N_ELEM + base;
    unsigned* rp = rp0 + (size_t)crow * N_ELEM;
    unsigned long long acc = 0;
    __shared__ unsigned long long red[4];

    if (n > 0 && n <= CAP) {
        __shared__ unsigned skS[CAP], syS[CAP];
        __shared__ unsigned cnt[256], bas[257], curq[256], ssc[256];
        cnt[t] = 0;
        __syncthreads();
        for (int p = t; p < n; p += 256)
            atomicAdd(&cnt[(r[p].y >> 18) & 255], 1u);
        __syncthreads();
        { // exclusive prefix over the 256 sub-bin counts (ladder scan)
            unsigned mine = cnt[t];
            ssc[t] = mine;
            __syncthreads();
            for (int off = 1; off < 256; off <<= 1) {
                unsigned v = (t >= off) ? ssc[t - off] : 0u;
                __syncthreads();
                ssc[t] += v;
                __syncthreads();
            }
            unsigned ex = ssc[t] - mine;
            bas[t] = ex;
            curq[t] = ex;
            if (t == 255) bas[256] = ssc[255];
        }
        __syncthreads();
        for (int p = t; p < n; p += 256) {
            uint2 e = r[p];
            unsigned pos = atomicAdd(&curq[(e.y >> 18) & 255], 1u);
            skS[pos] = e.x;
            syS[pos] = e.y;
        }
        __syncthreads();
        for (int p = t; p < n; p += 256) {
            unsigned y = syS[p];
            unsigned sub = (y >> 18) & 255;
            unsigned lo = bas[sub], hi = bas[sub + 1];
            unsigned myKey = skS[p];
            unsigned cb = 0;
            for (unsigned k = lo; k < hi; k++) {
                unsigned K = skS[k];
                cb += (K < myKey || (K == myKey && k < (unsigned)p)) ? 1u : 0u;
            }
            unsigned rank = base + lo + cb + 1u;
            unsigned idx = y & 0x3FFFFu;
            if (!side)
                rp[idx] = rank;
            else
                acc += (unsigned long long)rp[idx] * (unsigned long long)rank;
        }
    } else if (n > CAP) { // safety fallback (not expected for N(0,1) inputs)
        for (int p = t; p < n; p += 256) {
            uint2 e = r[p];
            unsigned sub = (e.y >> 18) & 255;
            unsigned cb = 0;
            for (int k = 0; k < n; k++) {
                uint2 ek = r[k];
                unsigned s2 = (ek.y >> 18) & 255;
                bool less =
                    (s2 < sub) ||
                    (s2 == sub &&
                     (ek.x < e.x || (ek.x == e.x && k < p)));
                cb += less ? 1u : 0u;
            }
            unsigned rank = base + cb + 1u;
            unsigned idx = e.y & 0x3FFFFu;
            if (!side)
                rp[idx] = rank;
            else
                acc += (unsigned long long)rp[idx] * (unsigned long long)rank;
        }
    }
    if (side) {
        for (int off = 32; off > 0; off >>= 1)
            acc += __shfl_down(acc, off, 64);
        if ((t & 63) == 0) red[t >> 6] = acc;
        __syncthreads();
        if (t == 0) {
            unsigned long long s = red[0] + red[1] + red[2] + red[3];
            if (s) atomicAdd(&S[r0 + crow], s);
        }
    }
}

// --- Kernel E: closed-form Pearson of two exact permutations + loss --------
__global__ void finalize_kernel(const unsigned long long* __restrict__ S, int B,
                                float* __restrict__ out) {
    __shared__ double sh[128];
    const int t = threadIdx.x;
    const double Nd = (double)N_ELEM;
    const double m = (Nd + 1.0) * 0.5;
    const double q = Nd * (Nd * Nd - 1.0) / 12.0;
    double c = 0.0;
    if (t < B) {
        double num = (double)(long long)S[t] - Nd * m * m;
        c = num / sqrt(q * q + 1e-8);
    }
    sh[t] = c;
    __syncthreads();
    for (int off = 64; off > 0; off >>= 1) {
        if (t < off) sh[t] += sh[t + off];
        __syncthreads();
    }
    double mean = sh[0] / (double)B;
    __syncthreads();
    double d = (t < B) ? (c - mean) : 0.0;
    sh[t] = d * d;
    __syncthreads();
    for (int off = 64; off > 0; off >>= 1) {
        if (t < off) sh[t] += sh[t + off];
        __syncthreads();
    }
    if (t == 0) {
        double var = sh[0] / (double)B;
        double stdv = sqrt(var) + 1e-8;
        double icir = mean / stdv;
        out[0] = (float)(-icir + 0.1 * stdv);
    }
}

extern "C" void kernel_launch(void* const* d_in, const int* in_sizes, int n_in,
                              void* d_out, int out_size, void* d_ws,
                              size_t ws_size, hipStream_t stream) {
    const float* pred = (const float*)d_in[0];
    const float* tru = (const float*)d_in[1];
    const int B = in_sizes[0] / N_ELEM; // 90

    char* ws = (char*)d_ws;
    unsigned long long* S = (unsigned long long*)ws;
    const size_t off0 = 4096;
    // per chunked row: bh 2*8*512*4 = 32KB, rec both sides 4MB, rp0 1MB
    const size_t bhRow = (size_t)2 * NBLK * NC * 4;
    const size_t recRow = (size_t)2 * N_ELEM * 8;
    const size_t rpRow = (size_t)N_ELEM * 4;
    const size_t perRow = bhRow + recRow + rpRow;
    int R = (int)((ws_size > off0 ? ws_size - off0 : 0) / perRow);
    if (R > B) R = B;
    if (R < 1) R = 1;

    unsigned* bh = (unsigned*)(ws + off0);
    uint2* rec = (uint2*)(ws + off0 + (size_t)R * bhRow);
    unsigned* rp0 = (unsigned*)(ws + off0 + (size_t)R * bhRow + (size_t)R * recRow);

    hipMemsetAsync(S, 0, (size_t)B * 8, stream);

    for (int r0 = 0; r0 < B; r0 += R) {
        int RR = (B - r0 < R) ? (B - r0) : R;
        int rowGroups = (RR + 7) / 8;
        hist_kernel<<<dim3(NBLK, 2 * RR), 256, 0, stream>>>(pred, tru, r0, bh);
        scan_kernel<<<2 * RR, NC, 0, stream>>>(bh);
        scatter_kernel<<<rowGroups * 16 * 8, 256, 0, stream>>>(pred, tru, r0,
                                                               RR, bh, rec);
        rank_kernel<<<rowGroups * NC * 8, 256, 0, stream>>>(rec, bh, rp0, S,
                                                            r0, RR, 0);
        rank_kernel<<<rowGroups * NC * 8, 256, 0, stream>>>(rec, bh, rp0, S,
                                                            r0, RR, 1);
    }
    finalize_kernel<<<1, 128, 0, stream>>>(S, B, (float*)d_out);
}

// Round 3
// 907.264 us; speedup vs baseline: 1.3740x; 1.3740x over previous
//
#include <hip/hip_runtime.h>
#include <stdint.h>

#define N_ELEM 262144
#define NC 512       /* coarse scatter buckets */
#define NFINE 131072 /* fine bins = NC * 256; equal-frequency => lambda ~2 */
#define TILE 8192    /* scatter tile: whole tile counting-sorted in LDS */
#define NBLK (N_ELEM / TILE) /* 32 */
#define CAP 1024 /* LDS capacity per coarse bucket; equal-freq => ~512+-15% */

__device__ __forceinline__ unsigned key_of(float x) {
    unsigned u = __float_as_uint(x);
    return u ^ ((u & 0x80000000u) ? 0xFFFFFFFFu : 0x80000000u);
}
// inverse of key_of (bijective): recover float from order-key
__device__ __forceinline__ float unkey(unsigned k) {
    unsigned u = (k & 0x80000000u) ? (k ^ 0x80000000u) : ~k;
    return __uint_as_float(u);
}

// --- Equal-frequency monotone binning ---------------------------------------
// Piecewise-linear approximation of the N(0,1) CDF: 32 segments of width 0.25
// over [-4,4) plus two tail segments. Bins per segment proportional to the
// Gaussian mass of the segment (sum = NFINE exactly). Monotonicity proof:
// within a segment, (x - x0)*slope with slope>0 then floor then clamp is
// monotone non-decreasing in float arithmetic; across a boundary the clamp
// bounds f <= base[s]+cnt[s]-1 < base[s+1]. Correctness of the whole pipeline
// only needs monotone non-decreasing (exact keys order within a fine bin);
// the distribution assumption only affects load balance, and the n>CAP
// fallback in rank_kernel guards arbitrary inputs.
__device__ __constant__ int d_base[35] = {
    0,      4,      11,     30,     75,     176,    389,    812,    1600,
    2979,   5247,   8752,   13843,  20790,  29699,  40435,  52592,  65536,
    78480,  90637,  101373, 110282, 117229, 122320, 125825, 128093, 129472,
    130260, 130683, 130896, 130997, 131042, 131061, 131068, 131072};
__device__ __constant__ float d_slope[34] = {
    1.0f,     28.0f,    76.0f,    180.0f,   404.0f,   852.0f,   1692.0f,
    3152.0f,  5516.0f,  9072.0f,  14020.0f, 20364.0f, 27788.0f, 35636.0f,
    42944.0f, 48628.0f, 51776.0f, 51776.0f, 48628.0f, 42944.0f, 35636.0f,
    27788.0f, 20364.0f, 14020.0f, 9072.0f,  5516.0f,  3152.0f,  1692.0f,
    852.0f,   404.0f,   180.0f,   76.0f,    28.0f,    1.0f};

__device__ __forceinline__ int fine_of_t(float x, const int* __restrict__ b,
                                         const float* __restrict__ sl) {
    int t = (int)floorf((x + 4.0f) * 4.0f); // saturating cvt: monotone
    int seg = t < 0 ? 0 : (t > 31 ? 33 : t + 1);
    float xlo = (seg == 0)
                    ? -8.0f
                    : ((seg == 33) ? 4.0f : (-4.0f + (float)(seg - 1) * 0.25f));
    int cnt = b[seg + 1] - b[seg];
    int v = (int)floorf((x - xlo) * sl[seg]);
    v = v < 0 ? 0 : (v > cnt - 1 ? cnt - 1 : v);
    return b[seg] + v;
}

// --- Kernel A: per-(rowside,block) histogram of 512 coarse buckets ---------
__global__ __launch_bounds__(256) void hist_kernel(
    const float* __restrict__ pred, const float* __restrict__ tru, int r0,
    unsigned* __restrict__ bh) {
    __shared__ unsigned h[NC];
    __shared__ int tb[35];
    __shared__ float ts[34];
    const int rs = blockIdx.y, blk = blockIdx.x;
    const int row = r0 + (rs >> 1);
    const float* x = (rs & 1) ? tru : pred;
    for (int i = threadIdx.x; i < NC; i += 256) h[i] = 0;
    if (threadIdx.x < 35) tb[threadIdx.x] = d_base[threadIdx.x];
    if (threadIdx.x < 34) ts[threadIdx.x] = d_slope[threadIdx.x];
    __syncthreads();
    const float4* p =
        (const float4*)(x + (size_t)row * N_ELEM + (size_t)blk * TILE);
    for (int i = threadIdx.x; i < TILE / 4; i += 256) {
        float4 v = p[i];
        atomicAdd(&h[fine_of_t(v.x, tb, ts) >> 8], 1u);
        atomicAdd(&h[fine_of_t(v.y, tb, ts) >> 8], 1u);
        atomicAdd(&h[fine_of_t(v.z, tb, ts) >> 8], 1u);
        atomicAdd(&h[fine_of_t(v.w, tb, ts) >> 8], 1u);
    }
    __syncthreads();
    unsigned* out = bh + ((size_t)rs * NBLK + blk) * NC;
    for (int i = threadIdx.x; i < NC; i += 256) out[i] = h[i];
}

// --- Kernel B: per-rowside scan -> per-block scatter starts ----------------
// After this, the blk-0 plane holds the rowside-level coarse exclusive prefix.
__global__ __launch_bounds__(512) void scan_kernel(unsigned* __restrict__ bh) {
    __shared__ unsigned ss[NC];
    const int rs = blockIdx.x;
    unsigned* p = bh + (size_t)rs * NBLK * NC;
    const int c = threadIdx.x; // one thread per coarse bucket
    unsigned cnts[NBLK];
    unsigned tot = 0;
    for (int b = 0; b < NBLK; b++) {
        cnts[b] = p[(size_t)b * NC + c];
        tot += cnts[b];
    }
    ss[c] = tot;
    __syncthreads();
    for (int off = 1; off < NC; off <<= 1) {
        unsigned v = (c >= off) ? ss[c - off] : 0u;
        __syncthreads();
        ss[c] += v;
        __syncthreads();
    }
    unsigned pre = ss[c] - tot; // exclusive
    for (int b = 0; b < NBLK; b++) {
        p[(size_t)b * NC + c] = pre;
        pre += cnts[b];
    }
}

// --- Kernel C: LDS counting-sort scatter -----------------------------------
// The whole 8192-element tile is bucket-sorted in LDS, then written back so
// consecutive threads store consecutive global addresses (runs of ~16 recs
// per bucket => ~128B bursts). This replaces per-lane random 8B stores whose
// 512-line write frontier per block overflowed L2 (R1: WRITE_SIZE 917MB =
// 4.9x ideal). Bucket id at writeback is recovered by inverting the order-key
// (bijective) through the same monotone table.
// XCD-pinned by row; all units of a rowside share one XCD so partial lines at
// run boundaries merge in that XCD's L2.
__global__ __launch_bounds__(512, 4) void scatter_kernel(
    const float* __restrict__ pred, const float* __restrict__ tru, int r0,
    int RR, const unsigned* __restrict__ bh, uint2* __restrict__ rec) {
    __shared__ unsigned sk[TILE];    // 32 KB sorted keys
    __shared__ unsigned sy[TILE];    // 32 KB sorted payloads
    __shared__ unsigned lh[NC];      // counts -> running cursor
    __shared__ unsigned lstart[NC];  // block-local exclusive prefix
    __shared__ unsigned gst[NC];     // global per-(block,bucket) start
    __shared__ unsigned swave[8];
    __shared__ int tb[35];
    __shared__ float ts[34];
    const int L = blockIdx.x;
    const int xcd = L & 7;
    const int m = L >> 3;
    const int unit = m & (2 * NBLK - 1); // side+blk, 64 units
    const int rowGroup = m >> 6;
    const int crow = rowGroup * 8 + xcd;
    if (crow >= RR) return;
    const int side = unit & 1, blk = unit >> 1;
    const int rs = crow * 2 + side;
    const int row = r0 + crow;
    const float* x = side ? tru : pred;
    const int t = threadIdx.x;
    if (t < NC) lh[t] = 0;
    if (t < 35) tb[t] = d_base[t];
    if (t < 34) ts[t] = d_slope[t];
    __syncthreads();
    const float4* p =
        (const float4*)(x + (size_t)row * N_ELEM + (size_t)blk * TILE);
    const int ib = blk * TILE;
    unsigned ky[16], yy[16];
    // pass 0: load, key, count
#pragma unroll
    for (int i = 0; i < 4; i++) {
        float4 v = p[t + i * 512];
        const int e0 = (t + i * 512) * 4;
        float vv[4] = {v.x, v.y, v.z, v.w};
#pragma unroll
        for (int k = 0; k < 4; k++) {
            float xv = vv[k];
            int f = fine_of_t(xv, tb, ts);
            ky[i * 4 + k] = key_of(xv);
            yy[i * 4 + k] =
                ((unsigned)(f & 255) << 18) | (unsigned)(ib + e0 + k);
            atomicAdd(&lh[f >> 8], 1u);
        }
    }
    __syncthreads();
    // exclusive scan of 512 counts: one thread per bucket, wave shfl scan
    {
        unsigned mine = lh[t];
        unsigned v = mine;
#pragma unroll
        for (int off = 1; off < 64; off <<= 1) {
            unsigned u = (unsigned)__shfl_up((int)v, off, 64);
            if ((t & 63) >= off) v += u;
        }
        if ((t & 63) == 63) swave[t >> 6] = v;
        __syncthreads();
        unsigned wo = 0;
        const int wid = t >> 6;
#pragma unroll
        for (int w = 0; w < 8; w++) wo += (w < wid) ? swave[w] : 0u;
        unsigned ex = v + wo - mine;
        lstart[t] = ex;
        lh[t] = ex; // cursor
        gst[t] = bh[((size_t)rs * NBLK + blk) * NC + t];
    }
    __syncthreads();
    // pass 1: place records bucket-sorted in LDS
#pragma unroll
    for (int i = 0; i < 16; i++) {
        int c = fine_of_t(unkey(ky[i]), tb, ts) >> 8;
        unsigned slot = atomicAdd(&lh[c], 1u);
        sk[slot] = ky[i];
        sy[slot] = yy[i];
    }
    __syncthreads();
    // pass 2: coalesced writeback in sorted order
    uint2* rr = rec + (size_t)rs * N_ELEM;
#pragma unroll
    for (int i = 0; i < 16; i++) {
        const int j = t + i * 512;
        unsigned k = sk[j];
        int c = fine_of_t(unkey(k), tb, ts) >> 8;
        unsigned g = gst[c] + (unsigned)j - lstart[c];
        rr[g] = make_uint2(k, sy[j]);
    }
}

// --- Kernel D: per coarse bucket: LDS counting-sort by 8-bit sub-bin, then
// exact in-sub-bin ordinal rank (~2 compares/element weighted, lambda~2).
// 1D grid, XCD-pinned by row so rp[idx] writes (side 0) / gathers (side 1)
// stay in one L2. side==0: rp0[idx]=rank; side==1: gather, acc S[row].
__global__ __launch_bounds__(256) void rank_kernel(
    const uint2* __restrict__ rec, const unsigned* __restrict__ bh,
    unsigned* __restrict__ rp0, unsigned long long* __restrict__ S, int r0,
    int RR, int side) {
    const int L = blockIdx.x;
    const int xcd = L & 7;
    const int m = L >> 3;
    const int c = m & (NC - 1);
    const int rowGroup = m / NC;
    const int crow = rowGroup * 8 + xcd;
    if (crow >= RR) return;
    const int rs = crow * 2 + side;
    const unsigned* pf = bh + (size_t)rs * NBLK * NC; // blk0 = rowside prefix
    const unsigned base = pf[c];
    const unsigned end = (c + 1 < NC) ? pf[c + 1] : (unsigned)N_ELEM;
    const int n = (int)(end - base);
    const int t = threadIdx.x;
    const uint2* r = rec + (size_t)rs * N_ELEM + base;
    unsigned* rp = rp0 + (size_t)crow * N_ELEM;
    unsigned long long acc = 0;
    __shared__ unsigned long long red[4];
    __shared__ unsigned wts[4];

    if (n > 0 && n <= CAP) {
        __shared__ unsigned skS[CAP], syS[CAP];
        __shared__ unsigned cnt[256], bas[257], curq[256];
        cnt[t] = 0;
        __syncthreads();
        for (int p = t; p < n; p += 256)
            atomicAdd(&cnt[(r[p].y >> 18) & 255], 1u);
        __syncthreads();
        { // exclusive prefix over 256 sub-bin counts: wave shfl scan
            unsigned mine = cnt[t];
            unsigned v = mine;
#pragma unroll
            for (int off = 1; off < 64; off <<= 1) {
                unsigned u = (unsigned)__shfl_up((int)v, off, 64);
                if ((t & 63) >= off) v += u;
            }
            if ((t & 63) == 63) wts[t >> 6] = v;
            __syncthreads();
            unsigned wo = 0;
            const int wid = t >> 6;
#pragma unroll
            for (int w = 0; w < 4; w++) wo += (w < wid) ? wts[w] : 0u;
            unsigned inc = v + wo;
            unsigned ex = inc - mine;
            bas[t] = ex;
            curq[t] = ex;
            if (t == 255) bas[256] = inc;
        }
        __syncthreads();
        for (int p = t; p < n; p += 256) {
            uint2 e = r[p];
            unsigned pos = atomicAdd(&curq[(e.y >> 18) & 255], 1u);
            skS[pos] = e.x;
            syS[pos] = e.y;
        }
        __syncthreads();
        for (int p = t; p < n; p += 256) {
            unsigned y = syS[p];
            unsigned sub = (y >> 18) & 255;
            unsigned lo = bas[sub], hi = bas[sub + 1];
            unsigned myKey = skS[p];
            unsigned cb = 0;
            for (unsigned k = lo; k < hi; k++) {
                unsigned K = skS[k];
                cb += (K < myKey || (K == myKey && k < (unsigned)p)) ? 1u : 0u;
            }
            unsigned rank = base + lo + cb + 1u;
            unsigned idx = y & 0x3FFFFu;
            if (!side)
                rp[idx] = rank;
            else
                acc += (unsigned long long)rp[idx] * (unsigned long long)rank;
        }
    } else if (n > CAP) { // safety fallback (not expected for N(0,1) inputs)
        for (int p = t; p < n; p += 256) {
            uint2 e = r[p];
            unsigned sub = (e.y >> 18) & 255;
            unsigned cb = 0;
            for (int k = 0; k < n; k++) {
                uint2 ek = r[k];
                unsigned s2 = (ek.y >> 18) & 255;
                bool less =
                    (s2 < sub) ||
                    (s2 == sub &&
                     (ek.x < e.x || (ek.x == e.x && k < p)));
                cb += less ? 1u : 0u;
            }
            unsigned rank = base + cb + 1u;
            unsigned idx = e.y & 0x3FFFFu;
            if (!side)
                rp[idx] = rank;
            else
                acc += (unsigned long long)rp[idx] * (unsigned long long)rank;
        }
    }
    if (side) {
        for (int off = 32; off > 0; off >>= 1)
            acc += __shfl_down(acc, off, 64);
        if ((t & 63) == 0) red[t >> 6] = acc;
        __syncthreads();
        if (t == 0) {
            unsigned long long s = red[0] + red[1] + red[2] + red[3];
            if (s) atomicAdd(&S[r0 + crow], s);
        }
    }
}

// --- Kernel E: closed-form Pearson of two exact permutations + loss --------
__global__ void finalize_kernel(const unsigned long long* __restrict__ S, int B,
                                float* __restrict__ out) {
    __shared__ double sh[128];
    const int t = threadIdx.x;
    const double Nd = (double)N_ELEM;
    const double m = (Nd + 1.0) * 0.5;
    const double q = Nd * (Nd * Nd - 1.0) / 12.0;
    double c = 0.0;
    if (t < B) {
        double num = (double)(long long)S[t] - Nd * m * m;
        c = num / sqrt(q * q + 1e-8);
    }
    sh[t] = c;
    __syncthreads();
    for (int off = 64; off > 0; off >>= 1) {
        if (t < off) sh[t] += sh[t + off];
        __syncthreads();
    }
    double mean = sh[0] / (double)B;
    __syncthreads();
    double d = (t < B) ? (c - mean) : 0.0;
    sh[t] = d * d;
    __syncthreads();
    for (int off = 64; off > 0; off >>= 1) {
        if (t < off) sh[t] += sh[t + off];
        __syncthreads();
    }
    if (t == 0) {
        double var = sh[0] / (double)B;
        double stdv = sqrt(var) + 1e-8;
        double icir = mean / stdv;
        out[0] = (float)(-icir + 0.1 * stdv);
    }
}

extern "C" void kernel_launch(void* const* d_in, const int* in_sizes, int n_in,
                              void* d_out, int out_size, void* d_ws,
                              size_t ws_size, hipStream_t stream) {
    const float* pred = (const float*)d_in[0];
    const float* tru = (const float*)d_in[1];
    const int B = in_sizes[0] / N_ELEM; // 90

    char* ws = (char*)d_ws;
    unsigned long long* S = (unsigned long long*)ws;
    const size_t off0 = 4096;
    // per chunked row: bh 2*32*512*4 = 128KB, rec both sides 4MB, rp0 1MB
    const size_t bhRow = (size_t)2 * NBLK * NC * 4;
    const size_t recRow = (size_t)2 * N_ELEM * 8;
    const size_t rpRow = (size_t)N_ELEM * 4;
    const size_t perRow = bhRow + recRow + rpRow;
    int R = (int)((ws_size > off0 ? ws_size - off0 : 0) / perRow);
    if (R > B) R = B;
    if (R < 1) R = 1;

    unsigned* bh = (unsigned*)(ws + off0);
    uint2* rec = (uint2*)(ws + off0 + (size_t)R * bhRow);
    unsigned* rp0 = (unsigned*)(ws + off0 + (size_t)R * bhRow + (size_t)R * recRow);

    hipMemsetAsync(S, 0, (size_t)B * 8, stream);

    for (int r0 = 0; r0 < B; r0 += R) {
        int RR = (B - r0 < R) ? (B - r0) : R;
        int rowGroups = (RR + 7) / 8;
        hist_kernel<<<dim3(NBLK, 2 * RR), 256, 0, stream>>>(pred, tru, r0, bh);
        scan_kernel<<<2 * RR, NC, 0, stream>>>(bh);
        scatter_kernel<<<rowGroups * 2 * NBLK * 8, 512, 0, stream>>>(
            pred, tru, r0, RR, bh, rec);
        rank_kernel<<<rowGroups * NC * 8, 256, 0, stream>>>(rec, bh, rp0, S,
                                                            r0, RR, 0);
        rank_kernel<<<rowGroups * NC * 8, 256, 0, stream>>>(rec, bh, rp0, S,
                                                            r0, RR, 1);
    }
    finalize_kernel<<<1, 128, 0, stream>>>(S, B, (float*)d_out);
}